// Round 7
// baseline (535.060 us; speedup 1.0000x reference)
//
#include <hip/hip_runtime.h>
#include <hip/hip_bf16.h>
#include <stdint.h>

typedef __bf16 bf16x8 __attribute__((ext_vector_type(8)));
typedef float  f32x4  __attribute__((ext_vector_type(4)));
typedef unsigned int u32x4 __attribute__((ext_vector_type(4)));
typedef unsigned short u16;
typedef unsigned int   u32;

#define B_  32
#define N_  128
#define F_  128
#define G_  300
#define GP  320   // G padded to multiple of 32
#define NTILE 36  // upper-triangle 16x16 tile-pairs
#define TILE_E 32768  // elements per tile: 16*16*128

__device__ __forceinline__ float b2f(u16 v){
  union { u32 u; float f; } x; x.u = ((u32)v) << 16; return x.f;
}
__device__ __forceinline__ u16 f2b(float f){
  union { float f; u32 u; } x; x.f = f;
  u32 r = x.u + 0x7FFFu + ((x.u >> 16) & 1u);
  return (u16)(r >> 16);
}
// pack 2 f32 -> 2 bf16 (round-half-up) in one u32: lo=a, hi=b
__device__ __forceinline__ u32 pk2(float a, float b){
  return __builtin_amdgcn_perm(__float_as_uint(b) + 0x8000u,
                               __float_as_uint(a) + 0x8000u, 0x07060302u);
}
// shifted softplus: ln2*(log2(1+2^(x*log2e)) - 1)
__device__ __forceinline__ float sspf(float x){
  return fmaf(0.69314718f, __log2f(1.0f + __builtin_amdgcn_exp2f(1.44269504f*x)),
              -0.69314718f);
}
__device__ __forceinline__ f32x4 mfma16(bf16x8 a, bf16x8 b, f32x4 c){
  return __builtin_amdgcn_mfma_f32_16x16x32_bf16(a, b, c, 0, 0, 0);
}

// ---------------- setup: transpose+cast weight matrices to bf16 ----------------
__global__ __launch_bounds__(256) void k_setup(const float* __restrict__ w_f1,
                                               const float* __restrict__ w_f2,
                                               const float* __restrict__ w_in2f,
                                               u16* __restrict__ w1t,
                                               u16* __restrict__ w2t,
                                               u16* __restrict__ wi2t){
  int idx = blockIdx.x*256 + threadIdx.x;
  if (idx < 128*GP){
    int k = idx / GP, g = idx % GP;
    w1t[idx] = (g < G_) ? f2b(w_f1[g*F_ + k]) : (u16)0;
  } else if (idx < 128*GP + 128*128){
    int j = idx - 128*GP; int h = j / 128, k = j % 128;
    w2t[h*128 + k] = f2b(w_f2[k*128 + h]);
  } else if (idx < 128*GP + 2*128*128){
    int j = idx - 128*GP - 128*128; int h = j / 128, ff = j % 128;
    wi2t[h*128 + ff] = f2b(w_in2f[ff*128 + h]);
  }
}

// ---------------- x = emb[z] (fp32) ----------------
__global__ __launch_bounds__(256) void k_embed(const int* __restrict__ z,
                                               const float* __restrict__ emb,
                                               float* __restrict__ x){
  int idx = blockIdx.x*256 + threadIdx.x;   // < 32*128*128
  int bn = idx >> 7, ff = idx & 127;
  x[idx] = emb[z[bn]*F_ + ff];
}

// ---------------- filter network, compact upper-triangle W ----------------
// block = (bl, tile-pair(ti<=tj), half): 8 i-rows x 16 j x 128 h.
// LDS exactly 32KB (5 blocks/CU); distances via per-wave shuffles.
__global__ __launch_bounds__(256, 5) void k_filter(const float* __restrict__ r,
                                                   const u16* __restrict__ w1t,
                                                   const u16* __restrict__ w2t,
                                                   const float* __restrict__ bf1,
                                                   const float* __restrict__ bf2,
                                                   u16* __restrict__ W,
                                                   int b0){
  __shared__ __attribute__((aligned(16))) u16 w1s[128*128];  // [p][f] XOR-even; reused for C2

  int tid = threadIdx.x, lane = tid & 63, wave = tid >> 6;
  int m = lane & 15, q = lane >> 4;

  int idx  = blockIdx.x;
  int half = idx & 1;
  int rem  = idx >> 1;
  int Tt   = rem % NTILE;
  int bl   = rem / NTILE;
  int b    = b0 + bl;
  int ti = 0;
  { int cnt = 8;
    while (Tt >= cnt){ Tt -= cnt; cnt--; ti++; } }
  int tj = ti + Tt;

  const float KS = 3.79828256f;              // sqrt(10*log2(e))
  const float KC = KS * (30.0f/299.0f);
  int rows0 = wave*32;                       // wave owns pairs [rows0, rows0+32)

  // per-wave distances: all 64 lanes compute pair rows0 + (lane&31)
  float dval;
  {
    int p  = rows0 + (lane & 31);
    const float* rb = r + (size_t)(b*N_)*3;
    int ii = ti*16 + half*8 + (p >> 4), jj = tj*16 + (p & 15);
    float dx = rb[ii*3]   - rb[jj*3];
    float dy = rb[ii*3+1] - rb[jj*3+1];
    float dz = rb[ii*3+2] - rb[jj*3+2];
    dval = KS * sqrtf(dx*dx + dy*dy + dz*dz + 1e-12f);
  }
  float sd0 = __shfl(dval, m, 64);
  float sd1 = __shfl(dval, 16 + m, 64);
  // per-wave min/max for gaussian-chunk skip
  float mn = dval, mx = dval;
  #pragma unroll
  for (int off = 16; off; off >>= 1){
    mn = fminf(mn, __shfl_xor(mn, off, 64));
    mx = fmaxf(mx, __shfl_xor(mx, off, 64));
  }
  int ks0 = (int)floorf((mn - 4.75f) / (32.0f*KC));
  int ks1 = (int)floorf((mx + 4.75f) / (32.0f*KC));
  ks0 = ks0 < 0 ? 0 : ks0;  ks1 = ks1 > 9 ? 9 : ks1;

  const float nkc2 = -KC*KC;
  const float tkc  = 2.0f*KC;
  const float srat = __builtin_amdgcn_exp2f(-2.0f*KC*KC);

  f32x4 acc1[8][2];
  #pragma unroll
  for (int ni = 0; ni < 8; ++ni){ acc1[ni][0] = (f32x4){0,0,0,0}; acc1[ni][1] = (f32x4){0,0,0,0}; }

  // ---- GEMM1: W1^T = w1t * rbf^T, K in [ks0*32, ks1*32+32) ----
  int vb = m*GP + q*8;
  bf16x8 a1c[8], a1n[8];
  #pragma unroll
  for (int ni = 0; ni < 8; ++ni)
    a1c[ni] = *reinterpret_cast<const bf16x8*>(w1t + vb + ni*16*GP + ks0*32);
  for (int ks = ks0; ks <= ks1; ++ks){
    if (ks < ks1){
      #pragma unroll
      for (int ni = 0; ni < 8; ++ni)
        a1n[ni] = *reinterpret_cast<const bf16x8*>(w1t + vb + ni*16*GP + (ks+1)*32);
    }
    float sct0 = KC * (float)(ks*32 + q*8);
    bf16x8 b1f[2];
    #pragma unroll
    for (int mi = 0; mi < 2; ++mi){
      float sd = mi ? sd1 : sd0;
      float t0 = sd - sct0;
      float fv0 = __builtin_amdgcn_exp2f(-(t0*t0));
      float rr_ = __builtin_amdgcn_exp2f(fmaf(tkc, t0, nkc2));
      float fv[8];
      fv[0] = fv0;
      #pragma unroll
      for (int t = 1; t < 8; ++t){ fv0 = fv0*rr_; rr_ = rr_*srat; fv[t] = fv0; }
      u32x4 au;
      #pragma unroll
      for (int t2 = 0; t2 < 4; ++t2) au[t2] = pk2(fv[t2*2], fv[t2*2+1]);
      b1f[mi] = __builtin_bit_cast(bf16x8, au);
    }
    #pragma unroll
    for (int ni = 0; ni < 8; ++ni){
      acc1[ni][0] = mfma16(a1c[ni], b1f[0], acc1[ni][0]);
      acc1[ni][1] = mfma16(a1c[ni], b1f[1], acc1[ni][1]);
    }
    #pragma unroll
    for (int ni = 0; ni < 8; ++ni) a1c[ni] = a1n[ni];
  }

  // ---- epilogue 1: +b_f1, ssp, pack -> w1s[p][f] (b64 writes, XOR-even) ----
  #pragma unroll
  for (int ni = 0; ni < 8; ++ni){
    float4 bia = *reinterpret_cast<const float4*>(bf1 + ni*16 + q*4);
    #pragma unroll
    for (int mi = 0; mi < 2; ++mi){
      int p = rows0 + mi*16 + m;
      u32 x0 = pk2(sspf(acc1[ni][mi][0] + bia.x), sspf(acc1[ni][mi][1] + bia.y));
      u32 x1 = pk2(sspf(acc1[ni][mi][2] + bia.z), sspf(acc1[ni][mi][3] + bia.w));
      int phys = (ni*4 + q) ^ (p & 30);
      *reinterpret_cast<uint2*>(&w1s[p*128 + phys*4]) = make_uint2(x0, x1);
    }
  }
  __syncthreads();

  // ---- GEMM2: W = W1 @ w_f2 (A=W1 from LDS b128, B=w2t from global L2) ----
  f32x4 acc2[8][2];
  #pragma unroll
  for (int ni = 0; ni < 8; ++ni){ acc2[ni][0] = (f32x4){0,0,0,0}; acc2[ni][1] = (f32x4){0,0,0,0}; }
  #pragma unroll
  for (int ks2 = 0; ks2 < 4; ++ks2){
    bf16x8 a2[2];
    #pragma unroll
    for (int mi = 0; mi < 2; ++mi){
      int p = rows0 + mi*16 + m;
      int phys = (ks2*8 + q*2) ^ (p & 30);
      a2[mi] = *reinterpret_cast<const bf16x8*>(&w1s[p*128 + phys*4]);
    }
    #pragma unroll
    for (int ni2 = 0; ni2 < 8; ++ni2){
      bf16x8 b2 = *reinterpret_cast<const bf16x8*>(w2t + (ni2*16 + m)*128 + ks2*32 + q*8);
      acc2[ni2][0] = mfma16(a2[0], b2, acc2[ni2][0]);
      acc2[ni2][1] = mfma16(a2[1], b2, acc2[ni2][1]);
    }
  }
  __syncthreads();   // w1s reads done; reuse as C2 buffer

  // ---- epilogue 2: +b_f2 -> w1s[p][h] (bf16, XOR-even) ----
  #pragma unroll
  for (int ni2 = 0; ni2 < 8; ++ni2){
    float bb = bf2[ni2*16 + m];
    #pragma unroll
    for (int mi = 0; mi < 2; ++mi)
      #pragma unroll
      for (int rr = 0; rr < 4; ++rr){
        int p = rows0 + mi*16 + q*4 + rr;
        int phys = (ni2*4 + (m >> 2)) ^ (p & 30);
        w1s[p*128 + phys*4 + (m & 3)] = f2b(acc2[ni2][mi][rr] + bb);
      }
  }
  __syncthreads();

  // ---- dense contiguous nt store into compact tile (no L2 allocate) ----
  int tIdx = ti*8 - (ti*(ti-1))/2 + (tj - ti);
  u16* Wt = W + ((size_t)bl*NTILE + tIdx)*TILE_E + half*16384;
  #pragma unroll
  for (int v = 0; v < 8; ++v){
    int o = v*2048 + tid*8;          // u16 offset in 16K half-tile
    int p = o >> 7;
    int g8 = (o & 127) >> 2;         // even
    int phys = g8 ^ (p & 30);
    u32x4 val = *reinterpret_cast<const u32x4*>(&w1s[p*128 + phys*4]);
    __builtin_nontemporal_store(val, reinterpret_cast<u32x4*>(Wt + o));
  }
}

// ---------------- f = x @ w_in2f (fp32 out), one block per b ----------------
__global__ __launch_bounds__(256) void k_inlin(const float* __restrict__ x,
                                               const u16* __restrict__ wi2t,
                                               float* __restrict__ f,
                                               int b0){
  __shared__ __attribute__((aligned(16))) u16 xa[128][136];
  __shared__ __attribute__((aligned(16))) u16 wb[128][136];
  int b = b0 + blockIdx.x;
  int tid = threadIdx.x, lane = tid & 63, wave = tid >> 6;
  int m = lane & 15, q = lane >> 4;
  {
    int row = tid >> 1, half = (tid & 1)*64;
    const float* src = x + ((size_t)b*N_ + row)*F_ + half;
    #pragma unroll
    for (int v = 0; v < 16; ++v){
      float4 t = *reinterpret_cast<const float4*>(src + v*4);
      xa[row][half + v*4]     = f2b(t.x);
      xa[row][half + v*4 + 1] = f2b(t.y);
      xa[row][half + v*4 + 2] = f2b(t.z);
      xa[row][half + v*4 + 3] = f2b(t.w);
    }
    const u16* s2 = wi2t + row*128 + half;
    #pragma unroll
    for (int v = 0; v < 8; ++v)
      *reinterpret_cast<bf16x8*>(&wb[row][half + v*8]) = *reinterpret_cast<const bf16x8*>(s2 + v*8);
  }
  __syncthreads();
  int jr = (wave >> 1)*64, kc = (wave & 1)*64;
  f32x4 acc[4][4];
  #pragma unroll
  for (int mi = 0; mi < 4; ++mi)
    #pragma unroll
    for (int ni = 0; ni < 4; ++ni) acc[mi][ni] = (f32x4){0.f,0.f,0.f,0.f};
  #pragma unroll
  for (int ks = 0; ks < 4; ++ks){
    int k0 = ks*32;
    bf16x8 af[4], bf[4];
    #pragma unroll
    for (int mi = 0; mi < 4; ++mi)
      af[mi] = *reinterpret_cast<const bf16x8*>(&xa[jr + mi*16 + m][k0 + q*8]);
    #pragma unroll
    for (int ni = 0; ni < 4; ++ni)
      bf[ni] = *reinterpret_cast<const bf16x8*>(&wb[kc + ni*16 + m][k0 + q*8]);
    #pragma unroll
    for (int mi = 0; mi < 4; ++mi)
      #pragma unroll
      for (int ni = 0; ni < 4; ++ni)
        acc[mi][ni] = mfma16(af[mi], bf[ni], acc[mi][ni]);
  }
  float* fp = f + (size_t)b*N_*F_;
  #pragma unroll
  for (int mi = 0; mi < 4; ++mi)
    #pragma unroll
    for (int ni = 0; ni < 4; ++ni)
      #pragma unroll
      for (int rr = 0; rr < 4; ++rr)
        fp[(jr + mi*16 + q*4 + rr)*F_ + kc + ni*16 + m] = acc[mi][ni][rr];
}

// ------- cfconv: one block per compact tile; y_i pass + transposed y_j pass ------
// writes deterministic 8-slot partials yp[bl][slot][row][h]; no LDS accumulation.
__global__ __launch_bounds__(256) void k_cfconv(const float* __restrict__ f,
                                                const u16* __restrict__ W,
                                                float* __restrict__ yp,
                                                int b0){
  __shared__ __attribute__((aligned(16))) float fA[16][132];
  __shared__ __attribute__((aligned(16))) float fB[16][132];

  int tid = threadIdx.x;
  int Tt = blockIdx.x % NTILE, bl = blockIdx.x / NTILE;
  int b = b0 + bl;
  int ti = 0;
  { int cnt = 8;
    while (Tt >= cnt){ Tt -= cnt; cnt--; ti++; } }
  int tj = ti + Tt;
  bool diag = (ti == tj);

  { // stage f tiles: fA = rows ti*16.., fB = rows tj*16..
    int tile = tid >> 7, tl = tid & 127;
    int row = tl >> 3, c0 = (tl & 7)*16;
    int base = (tile ? tj : ti)*16;
    const float* src = f + ((size_t)b*N_ + base + row)*F_ + c0;
    float* dst = tile ? &fB[row][c0] : &fA[row][c0];
    #pragma unroll
    for (int v = 0; v < 4; ++v)
      *reinterpret_cast<float4*>(dst + v*4) = *reinterpret_cast<const float4*>(src + v*4);
  }
  __syncthreads();

  int il = tid >> 4, hq = tid & 15, h0 = hq*8;
  int tIdx = ti*8 - (ti*(ti-1))/2 + (tj - ti);
  const u16* Wt = W + ((size_t)bl*NTILE + tIdx)*TILE_E;

  // pass 1: y_i[il] = sum_jl W[il][jl][h] * fB[jl][h]
  float yi[8] = {0,0,0,0,0,0,0,0};
  #pragma unroll 4
  for (int s = 0; s < 16; ++s){
    u32x4 wu = *reinterpret_cast<const u32x4*>(Wt + (il*16 + s)*128 + h0);
    bf16x8 w8 = __builtin_bit_cast(bf16x8, wu);
    float4 fa = *reinterpret_cast<const float4*>(&fB[s][h0]);
    float4 fb = *reinterpret_cast<const float4*>(&fB[s][h0 + 4]);
    yi[0] += (float)w8[0]*fa.x; yi[1] += (float)w8[1]*fa.y;
    yi[2] += (float)w8[2]*fa.z; yi[3] += (float)w8[3]*fa.w;
    yi[4] += (float)w8[4]*fb.x; yi[5] += (float)w8[5]*fb.y;
    yi[6] += (float)w8[6]*fb.z; yi[7] += (float)w8[7]*fb.w;
  }
  float* dst = yp + (((size_t)bl*8 + tj)*128 + ti*16 + il)*128 + h0;
  *reinterpret_cast<float4*>(dst)     = make_float4(yi[0], yi[1], yi[2], yi[3]);
  *reinterpret_cast<float4*>(dst + 4) = make_float4(yi[4], yi[5], yi[6], yi[7]);

  if (!diag){
    // pass 2: y_j[il] = sum_s W[s][il][h] * fA[s][h]  (transposed reads, L1/L2-hot)
    float yj[8] = {0,0,0,0,0,0,0,0};
    #pragma unroll 4
    for (int s = 0; s < 16; ++s){
      u32x4 wu = *reinterpret_cast<const u32x4*>(Wt + (s*16 + il)*128 + h0);
      bf16x8 w8 = __builtin_bit_cast(bf16x8, wu);
      float4 fa = *reinterpret_cast<const float4*>(&fA[s][h0]);
      float4 fb = *reinterpret_cast<const float4*>(&fA[s][h0 + 4]);
      yj[0] += (float)w8[0]*fa.x; yj[1] += (float)w8[1]*fa.y;
      yj[2] += (float)w8[2]*fa.z; yj[3] += (float)w8[3]*fa.w;
      yj[4] += (float)w8[4]*fb.x; yj[5] += (float)w8[5]*fb.y;
      yj[6] += (float)w8[6]*fb.z; yj[7] += (float)w8[7]*fb.w;
    }
    float* dst2 = yp + (((size_t)bl*8 + ti)*128 + tj*16 + il)*128 + h0;
    *reinterpret_cast<float4*>(dst2)     = make_float4(yj[0], yj[1], yj[2], yj[3]);
    *reinterpret_cast<float4*>(dst2 + 4) = make_float4(yj[4], yj[5], yj[6], yj[7]);
  }
}

// ------- mlp: reduce 8 slots -> y; y2=ssp(y@w_f2out+b); v=y2@w_out+b; x+=v -------
// block = (b, 8-row group), float4-wide threads
__global__ __launch_bounds__(256) void k_mlp(const float* __restrict__ yp,
                                             const float* __restrict__ w_f2out,
                                             const float* __restrict__ b_f2out,
                                             const float* __restrict__ w_out,
                                             const float* __restrict__ b_out,
                                             float* __restrict__ x,
                                             int b0){
  __shared__ float ysh[8][132];
  int bl = blockIdx.x >> 4, R = blockIdx.x & 15;
  int b  = b0 + bl;
  int tid = threadIdx.x;
  int il = tid >> 5, hq = tid & 31, h0 = hq*4;
  int row = R*8 + il;

  float4 y = make_float4(0,0,0,0);
  #pragma unroll
  for (int s = 0; s < 8; ++s){
    float4 a = *reinterpret_cast<const float4*>(
      yp + (((size_t)bl*8 + s)*128 + row)*128 + h0);
    y.x += a.x; y.y += a.y; y.z += a.z; y.w += a.w;
  }
  *reinterpret_cast<float4*>(&ysh[il][h0]) = y;
  __syncthreads();

  float4 y2 = make_float4(0,0,0,0);
  for (int k = 0; k < 128; ++k){
    float yv = ysh[il][k];
    float4 wa = *reinterpret_cast<const float4*>(w_f2out + k*F_ + h0);
    y2.x += yv*wa.x; y2.y += yv*wa.y; y2.z += yv*wa.z; y2.w += yv*wa.w;
  }
  float4 bb = *reinterpret_cast<const float4*>(b_f2out + h0);
  y2.x = sspf(y2.x + bb.x); y2.y = sspf(y2.y + bb.y);
  y2.z = sspf(y2.z + bb.z); y2.w = sspf(y2.w + bb.w);
  __syncthreads();
  *reinterpret_cast<float4*>(&ysh[il][h0]) = y2;
  __syncthreads();

  float4 v2 = make_float4(0,0,0,0);
  for (int k = 0; k < 128; ++k){
    float yv = ysh[il][k];
    float4 wa = *reinterpret_cast<const float4*>(w_out + k*F_ + h0);
    v2.x += yv*wa.x; v2.y += yv*wa.y; v2.z += yv*wa.z; v2.w += yv*wa.w;
  }
  float4 bo = *reinterpret_cast<const float4*>(b_out + h0);
  float* xp = x + ((size_t)b*N_ + row)*F_ + h0;
  float4 xv = *reinterpret_cast<const float4*>(xp);
  xv.x += v2.x + bo.x; xv.y += v2.y + bo.y;
  xv.z += v2.z + bo.z; xv.w += v2.w + bo.w;
  *reinterpret_cast<float4*>(xp) = xv;
}

// ---------------- readout: out = ssp(x@w_aw1+b)@w_aw2 + b2 ----------------
__global__ __launch_bounds__(256) void k_readout(const float* __restrict__ x,
                                                 const float* __restrict__ w_aw1,
                                                 const float* __restrict__ b_aw1,
                                                 const float* __restrict__ w_aw2,
                                                 const float* __restrict__ b_aw2,
                                                 float* __restrict__ out){
  int tid = threadIdx.x, lane = tid & 63, wave = tid >> 6;
  int atom = blockIdx.x*4 + wave;           // < 4096
  const float* xr = x + (size_t)atom*F_;
  float a0 = 0.f, a1 = 0.f;
  int f0 = lane, f1 = lane + 64;
  for (int k = 0; k < 128; ++k){
    float xv = xr[k];
    a0 += xv*w_aw1[k*F_ + f0];
    a1 += xv*w_aw1[k*F_ + f1];
  }
  float h0 = sspf(a0 + b_aw1[f0]);
  float h1 = sspf(a1 + b_aw1[f1]);
  float s = h0*w_aw2[f0] + h1*w_aw2[f1];
  #pragma unroll
  for (int off = 32; off; off >>= 1) s += __shfl_down(s, off, 64);
  if (lane == 0) out[atom] = s + b_aw2[0];
}

extern "C" void kernel_launch(void* const* d_in, const int* in_sizes, int n_in,
                              void* d_out, int out_size, void* d_ws, size_t ws_size,
                              hipStream_t stream){
  const int*   z       = (const int*)d_in[0];
  const float* r       = (const float*)d_in[1];
  const float* emb     = (const float*)d_in[2];
  const float* w_in2f  = (const float*)d_in[3];
  const float* w_f1    = (const float*)d_in[4];
  const float* b_f1    = (const float*)d_in[5];
  const float* w_f2    = (const float*)d_in[6];
  const float* b_f2    = (const float*)d_in[7];
  const float* w_f2out = (const float*)d_in[8];
  const float* b_f2out = (const float*)d_in[9];
  const float* w_out   = (const float*)d_in[10];
  const float* b_out   = (const float*)d_in[11];
  const float* w_aw1   = (const float*)d_in[12];
  const float* b_aw1   = (const float*)d_in[13];
  const float* w_aw2   = (const float*)d_in[14];
  const float* b_aw2   = (const float*)d_in[15];

  char* ws = (char*)d_ws;
  float* x    = (float*)(ws);                        // 2,097,152 B
  float* f    = (float*)(ws + 2097152);              // 2,097,152 B
  u16*   w1t  = (u16*)(ws + 4194304);                //    81,920 B
  u16*   w2t  = (u16*)(ws + 4276224);                //    32,768 B
  u16*   wi2t = (u16*)(ws + 4308992);                //    32,768 B
  const size_t SMALL_END = 4341760;
  const size_t WB  = (size_t)NTILE*TILE_E*2;         // 2,359,296 B per batch elem
  const size_t YPB = (size_t)8*128*128*4;            // 524,288 B per batch elem

  int chunk_b = 1;
  if (ws_size > SMALL_END + WB + YPB){
    size_t cb = (ws_size - SMALL_END) / (WB + YPB);
    if (cb >= 32)      chunk_b = 32;
    else if (cb >= 16) chunk_b = 16;
    else               chunk_b = (int)cb;
  }
  u16*   W  = (u16*)(ws + SMALL_END);
  float* yp = (float*)(ws + SMALL_END + (size_t)chunk_b*WB);

  k_setup<<<288, 256, 0, stream>>>(w_f1, w_f2, w_in2f, w1t, w2t, wi2t);
  k_embed<<<2048, 256, 0, stream>>>(z, emb, x);
  for (int b0 = 0; b0 < B_; b0 += chunk_b){
    int cb = (B_ - b0 < chunk_b) ? (B_ - b0) : chunk_b;
    k_filter<<<cb*NTILE*2, 256, 0, stream>>>(r, w1t, w2t, b_f1, b_f2, W, b0);
    for (int it = 0; it < 3; ++it){
      k_inlin<<<cb, 256, 0, stream>>>(x, wi2t, f, b0);
      k_cfconv<<<cb*NTILE, 256, 0, stream>>>(f, W, yp, b0);
      k_mlp<<<cb*16, 256, 0, stream>>>(yp, w_f2out, b_f2out, w_out, b_out, x, b0);
    }
  }
  k_readout<<<1024, 256, 0, stream>>>(x, w_aw1, b_aw1, w_aw2, b_aw2, (float*)d_out);
}

// Round 8
// 389.296 us; speedup vs baseline: 1.3744x; 1.3744x over previous
//
#include <hip/hip_runtime.h>
#include <hip/hip_bf16.h>
#include <stdint.h>

typedef __bf16 bf16x8 __attribute__((ext_vector_type(8)));
typedef float  f32x4  __attribute__((ext_vector_type(4)));
typedef unsigned int u32x4 __attribute__((ext_vector_type(4)));
typedef unsigned short u16;
typedef unsigned int   u32;

#define B_  32
#define N_  128
#define F_  128
#define G_  300
#define GP  320   // G padded to multiple of 32
#define NTILE 36  // upper-triangle 16x16 tile-pairs
#define TILE_E 32768  // elements per tile: 16*16*128

__device__ __forceinline__ float b2f(u16 v){
  union { u32 u; float f; } x; x.u = ((u32)v) << 16; return x.f;
}
__device__ __forceinline__ u16 f2b(float f){
  union { float f; u32 u; } x; x.f = f;
  u32 r = x.u + 0x7FFFu + ((x.u >> 16) & 1u);
  return (u16)(r >> 16);
}
// pack 2 f32 -> 2 bf16 (round-half-up) in one u32: lo=a, hi=b
__device__ __forceinline__ u32 pk2(float a, float b){
  return __builtin_amdgcn_perm(__float_as_uint(b) + 0x8000u,
                               __float_as_uint(a) + 0x8000u, 0x07060302u);
}
// shifted softplus: ln2*(log2(1+2^(x*log2e)) - 1)
__device__ __forceinline__ float sspf(float x){
  return fmaf(0.69314718f, __log2f(1.0f + __builtin_amdgcn_exp2f(1.44269504f*x)),
              -0.69314718f);
}
__device__ __forceinline__ f32x4 mfma16(bf16x8 a, bf16x8 b, f32x4 c){
  return __builtin_amdgcn_mfma_f32_16x16x32_bf16(a, b, c, 0, 0, 0);
}

// ---------------- setup: transpose+cast weight matrices to bf16 ----------------
__global__ __launch_bounds__(256) void k_setup(const float* __restrict__ w_f1,
                                               const float* __restrict__ w_f2,
                                               const float* __restrict__ w_in2f,
                                               u16* __restrict__ w1t,
                                               u16* __restrict__ w2t,
                                               u16* __restrict__ wi2t){
  int idx = blockIdx.x*256 + threadIdx.x;
  if (idx < 128*GP){
    int k = idx / GP, g = idx % GP;
    w1t[idx] = (g < G_) ? f2b(w_f1[g*F_ + k]) : (u16)0;
  } else if (idx < 128*GP + 128*128){
    int j = idx - 128*GP; int h = j / 128, k = j % 128;
    w2t[h*128 + k] = f2b(w_f2[k*128 + h]);
  } else if (idx < 128*GP + 2*128*128){
    int j = idx - 128*GP - 128*128; int h = j / 128, ff = j % 128;
    wi2t[h*128 + ff] = f2b(w_in2f[ff*128 + h]);
  }
}

// ---------------- x = emb[z] (fp32) ----------------
__global__ __launch_bounds__(256) void k_embed(const int* __restrict__ z,
                                               const float* __restrict__ emb,
                                               float* __restrict__ x){
  int idx = blockIdx.x*256 + threadIdx.x;   // < 32*128*128
  int bn = idx >> 7, ff = idx & 127;
  x[idx] = emb[z[bn]*F_ + ff];
}

// ---------------- filter network, compact upper-triangle W ----------------
// block = (bl, tile-pair(ti<=tj), half): 8 i-rows x 16 j x 128 h.
// LDS exactly 32KB; distances via per-wave shuffles.
// launch_bounds(256,4): cap=128 VGPR >= natural ~88 -> NO SPILL (R7's (256,5) spilled).
__global__ __launch_bounds__(256, 4) void k_filter(const float* __restrict__ r,
                                                   const u16* __restrict__ w1t,
                                                   const u16* __restrict__ w2t,
                                                   const float* __restrict__ bf1,
                                                   const float* __restrict__ bf2,
                                                   u16* __restrict__ W,
                                                   int b0){
  __shared__ __attribute__((aligned(16))) u16 w1s[128*128];  // [p][f] XOR-even; reused for C2

  int tid = threadIdx.x, lane = tid & 63, wave = tid >> 6;
  int m = lane & 15, q = lane >> 4;

  int idx  = blockIdx.x;
  int half = idx & 1;
  int rem  = idx >> 1;
  int Tt   = rem % NTILE;
  int bl   = rem / NTILE;
  int b    = b0 + bl;
  int ti = 0;
  { int cnt = 8;
    while (Tt >= cnt){ Tt -= cnt; cnt--; ti++; } }
  int tj = ti + Tt;

  const float KS = 3.79828256f;              // sqrt(10*log2(e))
  const float KC = KS * (30.0f/299.0f);
  int rows0 = wave*32;                       // wave owns pairs [rows0, rows0+32)

  // per-wave distances: all 64 lanes compute pair rows0 + (lane&31)
  float dval;
  {
    int p  = rows0 + (lane & 31);
    const float* rb = r + (size_t)(b*N_)*3;
    int ii = ti*16 + half*8 + (p >> 4), jj = tj*16 + (p & 15);
    float dx = rb[ii*3]   - rb[jj*3];
    float dy = rb[ii*3+1] - rb[jj*3+1];
    float dz = rb[ii*3+2] - rb[jj*3+2];
    dval = KS * sqrtf(dx*dx + dy*dy + dz*dz + 1e-12f);
  }
  float sd0 = __shfl(dval, m, 64);
  float sd1 = __shfl(dval, 16 + m, 64);
  // per-wave min/max for gaussian-chunk skip
  float mn = dval, mx = dval;
  #pragma unroll
  for (int off = 16; off; off >>= 1){
    mn = fminf(mn, __shfl_xor(mn, off, 64));
    mx = fmaxf(mx, __shfl_xor(mx, off, 64));
  }
  int ks0 = (int)floorf((mn - 4.75f) / (32.0f*KC));
  int ks1 = (int)floorf((mx + 4.75f) / (32.0f*KC));
  ks0 = ks0 < 0 ? 0 : ks0;  ks1 = ks1 > 9 ? 9 : ks1;

  const float nkc2 = -KC*KC;
  const float tkc  = 2.0f*KC;
  const float srat = __builtin_amdgcn_exp2f(-2.0f*KC*KC);

  f32x4 acc1[8][2];
  #pragma unroll
  for (int ni = 0; ni < 8; ++ni){ acc1[ni][0] = (f32x4){0,0,0,0}; acc1[ni][1] = (f32x4){0,0,0,0}; }

  // ---- GEMM1: W1^T = w1t * rbf^T, K in [ks0*32, ks1*32+32) ----
  int vb = m*GP + q*8;
  bf16x8 a1c[8], a1n[8];
  #pragma unroll
  for (int ni = 0; ni < 8; ++ni)
    a1c[ni] = *reinterpret_cast<const bf16x8*>(w1t + vb + ni*16*GP + ks0*32);
  for (int ks = ks0; ks <= ks1; ++ks){
    if (ks < ks1){
      #pragma unroll
      for (int ni = 0; ni < 8; ++ni)
        a1n[ni] = *reinterpret_cast<const bf16x8*>(w1t + vb + ni*16*GP + (ks+1)*32);
    }
    float sct0 = KC * (float)(ks*32 + q*8);
    bf16x8 b1f[2];
    #pragma unroll
    for (int mi = 0; mi < 2; ++mi){
      float sd = mi ? sd1 : sd0;
      float t0 = sd - sct0;
      float fv0 = __builtin_amdgcn_exp2f(-(t0*t0));
      float rr_ = __builtin_amdgcn_exp2f(fmaf(tkc, t0, nkc2));
      float fv[8];
      fv[0] = fv0;
      #pragma unroll
      for (int t = 1; t < 8; ++t){ fv0 = fv0*rr_; rr_ = rr_*srat; fv[t] = fv0; }
      u32x4 au;
      #pragma unroll
      for (int t2 = 0; t2 < 4; ++t2) au[t2] = pk2(fv[t2*2], fv[t2*2+1]);
      b1f[mi] = __builtin_bit_cast(bf16x8, au);
    }
    #pragma unroll
    for (int ni = 0; ni < 8; ++ni){
      acc1[ni][0] = mfma16(a1c[ni], b1f[0], acc1[ni][0]);
      acc1[ni][1] = mfma16(a1c[ni], b1f[1], acc1[ni][1]);
    }
    #pragma unroll
    for (int ni = 0; ni < 8; ++ni) a1c[ni] = a1n[ni];
  }

  // ---- epilogue 1: +b_f1, ssp, pack -> w1s[p][f] (b64 writes, XOR-even) ----
  #pragma unroll
  for (int ni = 0; ni < 8; ++ni){
    float4 bia = *reinterpret_cast<const float4*>(bf1 + ni*16 + q*4);
    #pragma unroll
    for (int mi = 0; mi < 2; ++mi){
      int p = rows0 + mi*16 + m;
      u32 x0 = pk2(sspf(acc1[ni][mi][0] + bia.x), sspf(acc1[ni][mi][1] + bia.y));
      u32 x1 = pk2(sspf(acc1[ni][mi][2] + bia.z), sspf(acc1[ni][mi][3] + bia.w));
      int phys = (ni*4 + q) ^ (p & 30);
      *reinterpret_cast<uint2*>(&w1s[p*128 + phys*4]) = make_uint2(x0, x1);
    }
  }
  __syncthreads();

  // ---- GEMM2: W = W1 @ w_f2 (A=W1 from LDS b128, B=w2t from global L2) ----
  f32x4 acc2[8][2];
  #pragma unroll
  for (int ni = 0; ni < 8; ++ni){ acc2[ni][0] = (f32x4){0,0,0,0}; acc2[ni][1] = (f32x4){0,0,0,0}; }
  #pragma unroll
  for (int ks2 = 0; ks2 < 4; ++ks2){
    bf16x8 a2[2];
    #pragma unroll
    for (int mi = 0; mi < 2; ++mi){
      int p = rows0 + mi*16 + m;
      int phys = (ks2*8 + q*2) ^ (p & 30);
      a2[mi] = *reinterpret_cast<const bf16x8*>(&w1s[p*128 + phys*4]);
    }
    #pragma unroll
    for (int ni2 = 0; ni2 < 8; ++ni2){
      bf16x8 b2 = *reinterpret_cast<const bf16x8*>(w2t + (ni2*16 + m)*128 + ks2*32 + q*8);
      acc2[ni2][0] = mfma16(a2[0], b2, acc2[ni2][0]);
      acc2[ni2][1] = mfma16(a2[1], b2, acc2[ni2][1]);
    }
  }
  __syncthreads();   // w1s reads done; reuse as C2 buffer

  // ---- epilogue 2: +b_f2 -> w1s[p][h] (bf16, XOR-even) ----
  #pragma unroll
  for (int ni2 = 0; ni2 < 8; ++ni2){
    float bb = bf2[ni2*16 + m];
    #pragma unroll
    for (int mi = 0; mi < 2; ++mi)
      #pragma unroll
      for (int rr = 0; rr < 4; ++rr){
        int p = rows0 + mi*16 + q*4 + rr;
        int phys = (ni2*4 + (m >> 2)) ^ (p & 30);
        w1s[p*128 + phys*4 + (m & 3)] = f2b(acc2[ni2][mi][rr] + bb);
      }
  }
  __syncthreads();

  // ---- dense contiguous nt store into compact tile (no L2 allocate) ----
  int tIdx = ti*8 - (ti*(ti-1))/2 + (tj - ti);
  u16* Wt = W + ((size_t)bl*NTILE + tIdx)*TILE_E + half*16384;
  #pragma unroll
  for (int v = 0; v < 8; ++v){
    int o = v*2048 + tid*8;          // u16 offset in 16K half-tile
    int p = o >> 7;
    int g8 = (o & 127) >> 2;         // even
    int phys = g8 ^ (p & 30);
    u32x4 val = *reinterpret_cast<const u32x4*>(&w1s[p*128 + phys*4]);
    __builtin_nontemporal_store(val, reinterpret_cast<u32x4*>(Wt + o));
  }
}

// ---------------- f = x @ w_in2f (fp32 out), one block per b ----------------
__global__ __launch_bounds__(256) void k_inlin(const float* __restrict__ x,
                                               const u16* __restrict__ wi2t,
                                               float* __restrict__ f,
                                               int b0){
  __shared__ __attribute__((aligned(16))) u16 xa[128][136];
  __shared__ __attribute__((aligned(16))) u16 wb[128][136];
  int b = b0 + blockIdx.x;
  int tid = threadIdx.x, lane = tid & 63, wave = tid >> 6;
  int m = lane & 15, q = lane >> 4;
  {
    int row = tid >> 1, half = (tid & 1)*64;
    const float* src = x + ((size_t)b*N_ + row)*F_ + half;
    #pragma unroll
    for (int v = 0; v < 16; ++v){
      float4 t = *reinterpret_cast<const float4*>(src + v*4);
      xa[row][half + v*4]     = f2b(t.x);
      xa[row][half + v*4 + 1] = f2b(t.y);
      xa[row][half + v*4 + 2] = f2b(t.z);
      xa[row][half + v*4 + 3] = f2b(t.w);
    }
    const u16* s2 = wi2t + row*128 + half;
    #pragma unroll
    for (int v = 0; v < 8; ++v)
      *reinterpret_cast<bf16x8*>(&wb[row][half + v*8]) = *reinterpret_cast<const bf16x8*>(s2 + v*8);
  }
  __syncthreads();
  int jr = (wave >> 1)*64, kc = (wave & 1)*64;
  f32x4 acc[4][4];
  #pragma unroll
  for (int mi = 0; mi < 4; ++mi)
    #pragma unroll
    for (int ni = 0; ni < 4; ++ni) acc[mi][ni] = (f32x4){0.f,0.f,0.f,0.f};
  #pragma unroll
  for (int ks = 0; ks < 4; ++ks){
    int k0 = ks*32;
    bf16x8 af[4], bf[4];
    #pragma unroll
    for (int mi = 0; mi < 4; ++mi)
      af[mi] = *reinterpret_cast<const bf16x8*>(&xa[jr + mi*16 + m][k0 + q*8]);
    #pragma unroll
    for (int ni = 0; ni < 4; ++ni)
      bf[ni] = *reinterpret_cast<const bf16x8*>(&wb[kc + ni*16 + m][k0 + q*8]);
    #pragma unroll
    for (int mi = 0; mi < 4; ++mi)
      #pragma unroll
      for (int ni = 0; ni < 4; ++ni)
        acc[mi][ni] = mfma16(af[mi], bf[ni], acc[mi][ni]);
  }
  float* fp = f + (size_t)b*N_*F_;
  #pragma unroll
  for (int mi = 0; mi < 4; ++mi)
    #pragma unroll
    for (int ni = 0; ni < 4; ++ni)
      #pragma unroll
      for (int rr = 0; rr < 4; ++rr)
        fp[(jr + mi*16 + q*4 + rr)*F_ + kc + ni*16 + m] = acc[mi][ni][rr];
}

// ------- cfconv: one block per compact tile; y_i pass + transposed y_j pass ------
// writes deterministic 8-slot partials yp[bl][slot][row][h]; no LDS accumulation.
__global__ __launch_bounds__(256) void k_cfconv(const float* __restrict__ f,
                                                const u16* __restrict__ W,
                                                float* __restrict__ yp,
                                                int b0){
  __shared__ __attribute__((aligned(16))) float fA[16][132];
  __shared__ __attribute__((aligned(16))) float fB[16][132];

  int tid = threadIdx.x;
  int Tt = blockIdx.x % NTILE, bl = blockIdx.x / NTILE;
  int b = b0 + bl;
  int ti = 0;
  { int cnt = 8;
    while (Tt >= cnt){ Tt -= cnt; cnt--; ti++; } }
  int tj = ti + Tt;
  bool diag = (ti == tj);

  { // stage f tiles: fA = rows ti*16.., fB = rows tj*16..
    int tile = tid >> 7, tl = tid & 127;
    int row = tl >> 3, c0 = (tl & 7)*16;
    int base = (tile ? tj : ti)*16;
    const float* src = f + ((size_t)b*N_ + base + row)*F_ + c0;
    float* dst = tile ? &fB[row][c0] : &fA[row][c0];
    #pragma unroll
    for (int v = 0; v < 4; ++v)
      *reinterpret_cast<float4*>(dst + v*4) = *reinterpret_cast<const float4*>(src + v*4);
  }
  __syncthreads();

  int il = tid >> 4, hq = tid & 15, h0 = hq*8;
  int tIdx = ti*8 - (ti*(ti-1))/2 + (tj - ti);
  const u16* Wt = W + ((size_t)bl*NTILE + tIdx)*TILE_E;

  // pass 1: y_i[il] = sum_jl W[il][jl][h] * fB[jl][h]
  float yi[8] = {0,0,0,0,0,0,0,0};
  #pragma unroll 4
  for (int s = 0; s < 16; ++s){
    u32x4 wu = *reinterpret_cast<const u32x4*>(Wt + (il*16 + s)*128 + h0);
    bf16x8 w8 = __builtin_bit_cast(bf16x8, wu);
    float4 fa = *reinterpret_cast<const float4*>(&fB[s][h0]);
    float4 fb = *reinterpret_cast<const float4*>(&fB[s][h0 + 4]);
    yi[0] += (float)w8[0]*fa.x; yi[1] += (float)w8[1]*fa.y;
    yi[2] += (float)w8[2]*fa.z; yi[3] += (float)w8[3]*fa.w;
    yi[4] += (float)w8[4]*fb.x; yi[5] += (float)w8[5]*fb.y;
    yi[6] += (float)w8[6]*fb.z; yi[7] += (float)w8[7]*fb.w;
  }
  float* dst = yp + (((size_t)bl*8 + tj)*128 + ti*16 + il)*128 + h0;
  *reinterpret_cast<float4*>(dst)     = make_float4(yi[0], yi[1], yi[2], yi[3]);
  *reinterpret_cast<float4*>(dst + 4) = make_float4(yi[4], yi[5], yi[6], yi[7]);

  if (!diag){
    // pass 2: y_j[il] = sum_s W[s][il][h] * fA[s][h]  (transposed reads, L1/L2-hot)
    float yj[8] = {0,0,0,0,0,0,0,0};
    #pragma unroll 4
    for (int s = 0; s < 16; ++s){
      u32x4 wu = *reinterpret_cast<const u32x4*>(Wt + (s*16 + il)*128 + h0);
      bf16x8 w8 = __builtin_bit_cast(bf16x8, wu);
      float4 fa = *reinterpret_cast<const float4*>(&fA[s][h0]);
      float4 fb = *reinterpret_cast<const float4*>(&fA[s][h0 + 4]);
      yj[0] += (float)w8[0]*fa.x; yj[1] += (float)w8[1]*fa.y;
      yj[2] += (float)w8[2]*fa.z; yj[3] += (float)w8[3]*fa.w;
      yj[4] += (float)w8[4]*fb.x; yj[5] += (float)w8[5]*fb.y;
      yj[6] += (float)w8[6]*fb.z; yj[7] += (float)w8[7]*fb.w;
    }
    float* dst2 = yp + (((size_t)bl*8 + ti)*128 + tj*16 + il)*128 + h0;
    *reinterpret_cast<float4*>(dst2)     = make_float4(yj[0], yj[1], yj[2], yj[3]);
    *reinterpret_cast<float4*>(dst2 + 4) = make_float4(yj[4], yj[5], yj[6], yj[7]);
  }
}

// ------- mlp: reduce 8 slots -> y; y2=ssp(y@w_f2out+b); v=y2@w_out+b; x+=v -------
// block = (b, 8-row group), float4-wide threads
__global__ __launch_bounds__(256) void k_mlp(const float* __restrict__ yp,
                                             const float* __restrict__ w_f2out,
                                             const float* __restrict__ b_f2out,
                                             const float* __restrict__ w_out,
                                             const float* __restrict__ b_out,
                                             float* __restrict__ x,
                                             int b0){
  __shared__ float ysh[8][132];
  int bl = blockIdx.x >> 4, R = blockIdx.x & 15;
  int b  = b0 + bl;
  int tid = threadIdx.x;
  int il = tid >> 5, hq = tid & 31, h0 = hq*4;
  int row = R*8 + il;

  float4 y = make_float4(0,0,0,0);
  #pragma unroll
  for (int s = 0; s < 8; ++s){
    float4 a = *reinterpret_cast<const float4*>(
      yp + (((size_t)bl*8 + s)*128 + row)*128 + h0);
    y.x += a.x; y.y += a.y; y.z += a.z; y.w += a.w;
  }
  *reinterpret_cast<float4*>(&ysh[il][h0]) = y;
  __syncthreads();

  float4 y2 = make_float4(0,0,0,0);
  for (int k = 0; k < 128; ++k){
    float yv = ysh[il][k];
    float4 wa = *reinterpret_cast<const float4*>(w_f2out + k*F_ + h0);
    y2.x += yv*wa.x; y2.y += yv*wa.y; y2.z += yv*wa.z; y2.w += yv*wa.w;
  }
  float4 bb = *reinterpret_cast<const float4*>(b_f2out + h0);
  y2.x = sspf(y2.x + bb.x); y2.y = sspf(y2.y + bb.y);
  y2.z = sspf(y2.z + bb.z); y2.w = sspf(y2.w + bb.w);
  __syncthreads();
  *reinterpret_cast<float4*>(&ysh[il][h0]) = y2;
  __syncthreads();

  float4 v2 = make_float4(0,0,0,0);
  for (int k = 0; k < 128; ++k){
    float yv = ysh[il][k];
    float4 wa = *reinterpret_cast<const float4*>(w_out + k*F_ + h0);
    v2.x += yv*wa.x; v2.y += yv*wa.y; v2.z += yv*wa.z; v2.w += yv*wa.w;
  }
  float4 bo = *reinterpret_cast<const float4*>(b_out + h0);
  float* xp = x + ((size_t)b*N_ + row)*F_ + h0;
  float4 xv = *reinterpret_cast<const float4*>(xp);
  xv.x += v2.x + bo.x; xv.y += v2.y + bo.y;
  xv.z += v2.z + bo.z; xv.w += v2.w + bo.w;
  *reinterpret_cast<float4*>(xp) = xv;
}

// ---------------- readout: out = ssp(x@w_aw1+b)@w_aw2 + b2 ----------------
__global__ __launch_bounds__(256) void k_readout(const float* __restrict__ x,
                                                 const float* __restrict__ w_aw1,
                                                 const float* __restrict__ b_aw1,
                                                 const float* __restrict__ w_aw2,
                                                 const float* __restrict__ b_aw2,
                                                 float* __restrict__ out){
  int tid = threadIdx.x, lane = tid & 63, wave = tid >> 6;
  int atom = blockIdx.x*4 + wave;           // < 4096
  const float* xr = x + (size_t)atom*F_;
  float a0 = 0.f, a1 = 0.f;
  int f0 = lane, f1 = lane + 64;
  for (int k = 0; k < 128; ++k){
    float xv = xr[k];
    a0 += xv*w_aw1[k*F_ + f0];
    a1 += xv*w_aw1[k*F_ + f1];
  }
  float h0 = sspf(a0 + b_aw1[f0]);
  float h1 = sspf(a1 + b_aw1[f1]);
  float s = h0*w_aw2[f0] + h1*w_aw2[f1];
  #pragma unroll
  for (int off = 32; off; off >>= 1) s += __shfl_down(s, off, 64);
  if (lane == 0) out[atom] = s + b_aw2[0];
}

extern "C" void kernel_launch(void* const* d_in, const int* in_sizes, int n_in,
                              void* d_out, int out_size, void* d_ws, size_t ws_size,
                              hipStream_t stream){
  const int*   z       = (const int*)d_in[0];
  const float* r       = (const float*)d_in[1];
  const float* emb     = (const float*)d_in[2];
  const float* w_in2f  = (const float*)d_in[3];
  const float* w_f1    = (const float*)d_in[4];
  const float* b_f1    = (const float*)d_in[5];
  const float* w_f2    = (const float*)d_in[6];
  const float* b_f2    = (const float*)d_in[7];
  const float* w_f2out = (const float*)d_in[8];
  const float* b_f2out = (const float*)d_in[9];
  const float* w_out   = (const float*)d_in[10];
  const float* b_out   = (const float*)d_in[11];
  const float* w_aw1   = (const float*)d_in[12];
  const float* b_aw1   = (const float*)d_in[13];
  const float* w_aw2   = (const float*)d_in[14];
  const float* b_aw2   = (const float*)d_in[15];

  char* ws = (char*)d_ws;
  float* x    = (float*)(ws);                        // 2,097,152 B
  float* f    = (float*)(ws + 2097152);              // 2,097,152 B
  u16*   w1t  = (u16*)(ws + 4194304);                //    81,920 B
  u16*   w2t  = (u16*)(ws + 4276224);                //    32,768 B
  u16*   wi2t = (u16*)(ws + 4308992);                //    32,768 B
  const size_t SMALL_END = 4341760;
  const size_t WB  = (size_t)NTILE*TILE_E*2;         // 2,359,296 B per batch elem
  const size_t YPB = (size_t)8*128*128*4;            // 524,288 B per batch elem

  int chunk_b = 1;
  if (ws_size > SMALL_END + WB + YPB){
    size_t cb = (ws_size - SMALL_END) / (WB + YPB);
    if (cb >= 32)      chunk_b = 32;
    else if (cb >= 16) chunk_b = 16;
    else               chunk_b = (int)cb;
  }
  u16*   W  = (u16*)(ws + SMALL_END);
  float* yp = (float*)(ws + SMALL_END + (size_t)chunk_b*WB);

  k_setup<<<288, 256, 0, stream>>>(w_f1, w_f2, w_in2f, w1t, w2t, wi2t);
  k_embed<<<2048, 256, 0, stream>>>(z, emb, x);
  for (int b0 = 0; b0 < B_; b0 += chunk_b){
    int cb = (B_ - b0 < chunk_b) ? (B_ - b0) : chunk_b;
    k_filter<<<cb*NTILE*2, 256, 0, stream>>>(r, w1t, w2t, b_f1, b_f2, W, b0);
    for (int it = 0; it < 3; ++it){
      k_inlin<<<cb, 256, 0, stream>>>(x, wi2t, f, b0);
      k_cfconv<<<cb*NTILE, 256, 0, stream>>>(f, W, yp, b0);
      k_mlp<<<cb*16, 256, 0, stream>>>(yp, w_f2out, b_f2out, w_out, b_out, x, b0);
    }
  }
  k_readout<<<1024, 256, 0, stream>>>(x, w_aw1, b_aw1, w_aw2, b_aw2, (float*)d_out);
}